// Round 2
// baseline (268.159 us; speedup 1.0000x reference)
//
#include <hip/hip_runtime.h>

// GCLSTM (ChebConv K=1 => edge_index unused; every node is an independent LSTM
// with shared weights). Fused persistent kernel, bf16 MFMA recurrence:
//   g = [H(64) | x(3) | 0-pad] @ [Theta; W_x; 0]   K=96, via mfma_f32_16x16x32_bf16
// Theta^T fragments are loaded to REGISTERS once (48 VGPR/wave) -- zero B-side
// LDS traffic in the timestep loop. A-tile (H^T per node, bf16) round-trips
// through LDS. Bias + peephole + gates in exact fp32; C state in registers.
// Structural floor: trans pipe (10 v_exp/v_rcp per element) ~ 43us.

#define T_STEPS 64
#define N_NODES 20000
#define F_INP   3
#define HD      64
#define G4      256    // 4*HD
#define KP      104    // padded bf16 K-stride: rows 0..63 H, 64..66 x, 67..95 zero
#define BM      80     // nodes per block
#define NBLK    250    // N_NODES / BM
#define NTHR    256

typedef __attribute__((ext_vector_type(8))) short bf16x8;
typedef __attribute__((ext_vector_type(4))) float f32x4;

__device__ __forceinline__ unsigned short f2bf(float f) {
    union { float f; unsigned u; } v; v.f = f;
    unsigned r = v.u + 0x7FFFu + ((v.u >> 16) & 1u);   // RNE
    return (unsigned short)(r >> 16);
}
__device__ __forceinline__ float sigf(float x) {
    return __builtin_amdgcn_rcpf(1.0f + __expf(-x));
}
__device__ __forceinline__ float tanhf_(float x) {
    return 2.0f * __builtin_amdgcn_rcpf(1.0f + __expf(-2.0f * x)) - 1.0f;
}

__global__ __launch_bounds__(NTHR, 1)
void gclstm_main(const float* __restrict__ x_seq,    // [T][N][3]
                 const float* __restrict__ W_x,      // [3][256]
                 const float* __restrict__ Theta,    // [64][256]
                 const float* __restrict__ b_conv,   // [256]
                 const float* __restrict__ b_gate,   // [256]
                 const float* __restrict__ w_ci,     // [64]
                 const float* __restrict__ w_cf,     // [64]
                 const float* __restrict__ w_co,     // [64]
                 float* __restrict__ partial)        // [NBLK][HD]
{
    __shared__ __align__(16) unsigned short Bl[G4 * KP];  // Theta^T bf16: [n][k], 53.2KB
    __shared__ __align__(16) unsigned short Al[BM * KP];  // H/x bf16:     [node][k], 16.6KB

    const int t   = threadIdx.x;
    const int blk = blockIdx.x;
    const int n0  = blk * BM;
    const int w   = t >> 6;        // wave 0..3
    const int l   = t & 63;        // lane
    const int ln  = l & 15;        // lane&15: A-row / B-col / C-col index
    const int lg  = l >> 4;        // lane group: k-octet select / C-row group
    const int d   = w * 16 + ln;   // this lane's hidden dim (gates phase)

    // ---- zero LDS (k-pad rows must be 0), then stage weights ----
    for (int i = t; i < (G4 * KP) / 2; i += NTHR) ((unsigned*)Bl)[i] = 0u;
    for (int i = t; i < (BM * KP) / 2; i += NTHR) ((unsigned*)Al)[i] = 0u;
    __syncthreads();
    for (int i = t; i < HD * G4; i += NTHR) {          // Theta [k][n] -> Bl[n][k]
        int k = i >> 8, n = i & 255;
        Bl[n * KP + k] = f2bf(Theta[i]);
    }
    for (int i = t; i < F_INP * G4; i += NTHR) {       // W_x rows -> k = 64..66
        int k = 64 + (i >> 8), n = i & 255;
        Bl[n * KP + k] = f2bf(W_x[i]);
    }
    if (t < BM * F_INP)                                 // x(ts=0) -> Al rows, k=64..66
        Al[(t / 3) * KP + 64 + (t % 3)] = f2bf(x_seq[(size_t)(n0) * F_INP + t]);
    __syncthreads();

    // ---- Theta fragments -> registers, once (B-frag: lane&15 = col) ----
    bf16x8 Breg[4][3];
    #pragma unroll
    for (int g = 0; g < 4; ++g)
        #pragma unroll
        for (int ks = 0; ks < 3; ++ks)
            Breg[g][ks] = *reinterpret_cast<const bf16x8*>(
                &Bl[(g * 64 + d) * KP + ks * 32 + lg * 8]);

    // fp32 bias + peephole for this lane's dim (exact, outside the bf16 GEMM)
    const float bI = b_conv[d]       + b_gate[d];
    const float bF = b_conv[64 + d]  + b_gate[64 + d];
    const float bC = b_conv[128 + d] + b_gate[128 + d];
    const float bO = b_conv[192 + d] + b_gate[192 + d];
    const float wci_ = w_ci[d], wcf_ = w_cf[d], wco_ = w_co[d];

    float creg[5][4];
    #pragma unroll
    for (int mi = 0; mi < 5; ++mi)
        #pragma unroll
        for (int r = 0; r < 4; ++r) creg[mi][r] = 0.0f;

    float hsum = 0.0f;   // final-H per-lane node sum (exact fp32)

    for (int ts = 0; ts < T_STEPS; ++ts) {
        // ---- GEMM: acc[mi][g] = A(H|x) . B(Theta|W_x), fp32 accumulate ----
        f32x4 acc[5][4];
        #pragma unroll
        for (int mi = 0; mi < 5; ++mi)
            #pragma unroll
            for (int g = 0; g < 4; ++g)
                acc[mi][g] = (f32x4){0.f, 0.f, 0.f, 0.f};

        #pragma unroll
        for (int ks = 0; ks < 3; ++ks) {
            bf16x8 Ar[5];
            #pragma unroll
            for (int mi = 0; mi < 5; ++mi)
                Ar[mi] = *reinterpret_cast<const bf16x8*>(
                    &Al[(mi * 16 + ln) * KP + ks * 32 + lg * 8]);
            #pragma unroll
            for (int mi = 0; mi < 5; ++mi)
                #pragma unroll
                for (int g = 0; g < 4; ++g)
                    acc[mi][g] = __builtin_amdgcn_mfma_f32_16x16x32_bf16(
                        Ar[mi], Breg[g][ks], acc[mi][g], 0, 0, 0);
        }
        __syncthreads();   // all A-reads done CU-wide before Al is rewritten

        // ---- gates (fp32). C/D layout: col=lane&15 (dim d), row=lg*4+r (node) ----
        #pragma unroll
        for (int mi = 0; mi < 5; ++mi) {
            #pragma unroll
            for (int r = 0; r < 4; ++r) {
                const int node = mi * 16 + lg * 4 + r;
                float C  = creg[mi][r];
                float gi = acc[mi][0][r] + bI + wci_ * C;
                float gf = acc[mi][1][r] + bF + wcf_ * C;
                float gc = acc[mi][2][r] + bC;
                float I  = sigf(gi);
                float Fg = sigf(gf);
                float Tc = tanhf_(gc);
                float Cn = Fg * C + I * Tc;
                float O  = sigf(acc[mi][3][r] + bO + wco_ * Cn);
                float Hn = O * tanhf_(Cn);
                creg[mi][r] = Cn;
                Al[node * KP + d] = f2bf(Hn);          // H_new -> A rows k=0..63
                if (ts == T_STEPS - 1) hsum += Hn;     // uniform branch, last step
            }
        }
        // stage x(ts+1) into A rows k=64..66 (disjoint from H writes)
        if (ts + 1 < T_STEPS && t < BM * F_INP)
            Al[(t / 3) * KP + 64 + (t % 3)] =
                f2bf(x_seq[(size_t)((ts + 1) * N_NODES + n0) * F_INP + t]);
        __syncthreads();   // writes visible before next iteration's A-reads
    }

    // ---- final-H node sum: lanes l, l+16, l+32, l+48 share dim d ----
    hsum += __shfl_down(hsum, 32);
    hsum += __shfl_down(hsum, 16);
    if (l < 16) partial[blk * HD + d] = hsum;   // d = w*16 + l
}

__global__ void reduce_head(const float* __restrict__ partial,  // [NBLK][HD]
                            const float* __restrict__ W_lin,    // [64][2]
                            const float* __restrict__ b_lin,    // [2]
                            float* __restrict__ out)            // [2]
{
    __shared__ float emb[HD];
    const int t = threadIdx.x;  // 64 threads
    float s = 0.0f;
    for (int b = 0; b < NBLK; ++b) s += partial[b * HD + t];
    emb[t] = s * (1.0f / (float)N_NODES);
    __syncthreads();
    if (t < 2) {
        float acc = b_lin[t];
        #pragma unroll
        for (int dd = 0; dd < HD; ++dd)
            acc = fmaf(emb[dd], W_lin[dd * 2 + t], acc);
        out[t] = acc;
    }
}

extern "C" void kernel_launch(void* const* d_in, const int* in_sizes, int n_in,
                              void* d_out, int out_size, void* d_ws, size_t ws_size,
                              hipStream_t stream) {
    const float* x_seq  = (const float*)d_in[0];
    // d_in[1] = edge_index (int64) -- unused: ChebConv K=1 has no neighbor aggregation
    const float* W_x    = (const float*)d_in[2];
    const float* Theta  = (const float*)d_in[3];
    const float* b_conv = (const float*)d_in[4];
    const float* b_gate = (const float*)d_in[5];
    const float* w_ci   = (const float*)d_in[6];
    const float* w_cf   = (const float*)d_in[7];
    const float* w_co   = (const float*)d_in[8];
    const float* W_lin  = (const float*)d_in[9];
    const float* b_lin  = (const float*)d_in[10];

    float* out     = (float*)d_out;
    float* partial = (float*)d_ws;   // NBLK*HD floats = 64000 B

    gclstm_main<<<NBLK, NTHR, 0, stream>>>(x_seq, W_x, Theta, b_conv, b_gate,
                                           w_ci, w_cf, w_co, partial);
    reduce_head<<<1, HD, 0, stream>>>(partial, W_lin, b_lin, out);
}